// Round 15
// baseline (1384.581 us; speedup 1.0000x reference)
//
#include <hip/hip_runtime.h>
#include <hip/hip_fp16.h>

// Workspace: 384 MiB.
//   A [0,128M):   q_h (64M) -> k_h/k_l -> qk (f32, 128M)
//   D [128,256M): qT_h/qT_l -> P (64M) + vT (64M)
//   E [256,384M): kk_h (64M) + val_h (64M)
// d_out scratch (dead before final GEMM): wq_h/l, wk_h, wv_h

using half8_t = __attribute__((ext_vector_type(8))) _Float16;
using f32x4   = __attribute__((ext_vector_type(4))) float;

static constexpr int NB = 8;
static constexpr int Sd = 2048;
static constexpr long MAT = (long)Sd * Sd;

__device__ __forceinline__ void gload16(const _Float16* g, _Float16* l) {
  __builtin_amdgcn_global_load_lds(
      (const __attribute__((address_space(1))) void*)g,
      (__attribute__((address_space(3))) void*)l, 16, 0, 0);
}
// gemm10's measured-best sync artifact: memory-clobbered barrier/vmcnt.
__device__ __forceinline__ void barrier_() { asm volatile("s_barrier" ::: "memory"); }
#define VMCNT(n) asm volatile("s_waitcnt vmcnt(" #n ")" ::: "memory")
#define SCHEDB() __builtin_amdgcn_sched_barrier(0)

// ---------------------------------------------------------------------------
// presplit: f32 -> fp16 hi (+ residual lo if SPLIT), scaled.
// ---------------------------------------------------------------------------
template<bool SPLIT>
__global__ __launch_bounds__(256) void presplit(const float* __restrict__ in,
    _Float16* __restrict__ h, _Float16* __restrict__ l, long n8, float scl)
{
  long i = (long)blockIdx.x * 256 + threadIdx.x;
  const long stride = (long)gridDim.x * 256;
  for (; i < n8; i += stride) {
    const f32x4* p = (const f32x4*)(in + i * 8);
    f32x4 a = p[0], b = p[1];
    half8_t hh, ll;
#pragma unroll
    for (int j = 0; j < 4; j++) {
      float x = a[j] * scl; _Float16 hv = (_Float16)x;
      hh[j] = hv; if constexpr (SPLIT) ll[j] = (_Float16)(x - (float)hv);
      float y = b[j] * scl; _Float16 hw = (_Float16)y;
      hh[4 + j] = hw; if constexpr (SPLIT) ll[4 + j] = (_Float16)(y - (float)hw);
    }
    *(half8_t*)(h + i * 8) = hh;
    if constexpr (SPLIT) *(half8_t*)(l + i * 8) = ll;
  }
}

// ---------------------------------------------------------------------------
// gemm15 (B^T form): C[i][j] = cscale * sum_k A[i][k]*B[j][k] (+ bias)
// = gemm10 (measured-best schedule) with B-DIRECT: B fragments loaded from
//   global/L2 straight into registers (no LDS for B). Cuts LDS traffic per
//   phase 128KB -> 80KB; B panels are L2/L3-resident (2x wave multiplicity);
//   B regs persist across a unit's {hi,lo} phases (gemm13's shared-B saving
//   without its same-phase lgkm chain). LDS = A ring-4 only (64KB).
// 256x256 tile, 8 waves (2x4), 512 threads, 16x16x32 MFMA, acc 8x4.
// Phase p (split: unit k=p>>1, seg p&1): {readA(p+1 frags, alt set) ->
//   stageA(p+3) -> [even: loadB(k+1, alt b-set)] -> SCHEDB -> 32 MFMA ->
//   VMCNT(6) -> barrier}.  FIFO ledger: 6 newest = {stageA(p+3)x2,
//   B(k+1)x4} in any intra-phase order -> forces stageA(p+2), published by
//   the barrier, read at p+1. Compiler auto-vmcnt covers B register loads.
//   Prologue: A0,A1,A2 + B0, VMCNT(6) [forces A0,A1]. Tail: VMCNT(0)@p=125.
// NSEG: 1 plain (K=2048); 2 = unit-major split {Ah(k),Al(k)} x shared B(k).
// BIAS: 0 none, 1 bias[n], 2 bias[m].
// OUT: 0 f32, 1 fp16, 2 split fp16 (x16), 3 fp16 hi-only (x16).
// ---------------------------------------------------------------------------
template<int NSEG, int BIAS, int OUT>
__global__ __launch_bounds__(512, 2) void gemm15(
    const _Float16* __restrict__ Ah, const _Float16* __restrict__ Al, long sA,
    const _Float16* __restrict__ Bh, long sB,
    const float* __restrict__ bias, float cscale,
    void* __restrict__ Cp, void* __restrict__ Clp, long sC)
{
  __shared__ __align__(16) _Float16 LA[4][8192];   // A ring-4 x 16KB only

  const int t = threadIdx.x, w = t >> 6, l = t & 63;

  // XCD swizzle: 512 wgs -> 64 consecutive per XCD (one batch per XCD)
  const int wg = blockIdx.x;
  const int swz = (wg & 7) * 64 + (wg >> 3);
  const int bz = swz >> 6, rem = swz & 63;
  const int by = rem >> 3, bx = rem & 7;

  const _Float16* PAh = Ah + (size_t)bz * sA + (size_t)(by * 256) * Sd;
  const _Float16* PBh = Bh + (size_t)bz * sB + (size_t)(bx * 256) * Sd;
  const _Float16* PAl = (NSEG == 2)
      ? Al + (size_t)bz * sA + (size_t)(by * 256) * Sd : PAh;

  // A staging geometry (r10 verbatim): slot S = i*512 + t -> row
  // 2*(S>>3)+(S&1), k-slot lk = ((S&7)>>1)^((S>>3)&3); dest linear slot*8.
  const int s7 = t & 7;
  const int lkS = (s7 >> 1) ^ ((t >> 3) & 3);
  const size_t srcoff = (size_t)(2 * (t >> 3) + (s7 & 1)) * Sd + lkS * 8;
  const int du0 = w * 512;

  // A read geometry (r10 involution, measured conflict-free)
  const int wm = (w >> 2) * 128, wn = (w & 3) * 64;
  const int lm = l & 15, lkr = l >> 4;
  const int sprime = ((lkr ^ ((lm >> 1) & 3)) << 1) | (lm & 1);
  const int aoff = (wm >> 1) * 128 + (lm >> 1) * 128 + sprime * 16;

  // B-direct base: fragment fb[n] = B[wn + n*16 + lm][k*32 + lkr*8 ..+8]
  const _Float16* pB = PBh + (size_t)(wn + lm) * Sd + lkr * 8;

  auto stageA = [&](int p) {   // 2 global_load_lds (A half-slab pair)
    const int slot = p & 3;
    const _Float16* base;
    if constexpr (NSEG == 2)
      base = ((p & 1) ? PAl : PAh) + (p >> 1) * 32;
    else
      base = PAh + p * 32;
    gload16(base + srcoff, LA[slot] + du0);
    gload16(base + srcoff + (size_t)128 * Sd, LA[slot] + du0 + 4096);
  };

  f32x4 acc[8][4] = {};
  half8_t a0[8], a1[8], b0[4], b1[4];

  auto readA = [&](int slot, half8_t (&fa)[8]) {   // 8 ds_read_b128
#pragma unroll
    for (int f = 0; f < 8; f++)
      fa[f] = *(const half8_t*)((const char*)LA[slot] + aoff + f * 1024);
  };
  auto loadB = [&](int k, half8_t (&fb)[4]) {      // 4 global 16B loads
    const _Float16* base = pB + k * 32;
#pragma unroll
    for (int n = 0; n < 4; n++)
      fb[n] = *(const half8_t*)(base + (size_t)(n * 16) * Sd);
  };
  auto mfma32 = [&](const half8_t (&fa)[8], const half8_t (&fb)[4]) {
    __builtin_amdgcn_s_setprio(1);
#pragma unroll
    for (int f = 0; f < 8; f++)
#pragma unroll
      for (int n = 0; n < 4; n++)
        acc[f][n] = __builtin_amdgcn_mfma_f32_16x16x32_f16(fa[f], fb[n], acc[f][n], 0, 0, 0);
    __builtin_amdgcn_s_setprio(0);
  };

  if constexpr (NSEG == 2) {
    // 128 phases (64 units x {hi,lo}); B shared per unit.
    stageA(0); stageA(1); stageA(2);
    loadB(0, b0);
    VMCNT(6);            // keeps {B0 x4, sA2 x2}; forces sA0, sA1
    barrier_();
    readA(0, a0);

#define UNIT15(K, BC, BN)                                                 \
    {                                                                     \
      const int k_ = (K);                                                 \
      const int pe = 2 * k_;                                              \
      /* even phase pe: consume (a0, BC) */                               \
      readA((pe + 1) & 3, a1);                                            \
      if (pe <= 124) stageA(pe + 3);                                      \
      if (k_ <= 62) loadB(k_ + 1, BN);                                    \
      SCHEDB();                                                           \
      mfma32(a0, BC);                                                     \
      if (pe <= 124) { VMCNT(6); }                                        \
      if (pe <= 125) barrier_();                                          \
      /* odd phase pe+1: consume (a1, BC) */                              \
      if (pe + 2 <= 127) readA((pe + 2) & 3, a0);                         \
      if (pe + 1 <= 124) stageA(pe + 4);                                  \
      SCHEDB();                                                           \
      mfma32(a1, BC);                                                     \
      if (pe + 1 <= 124)      { VMCNT(6); }                               \
      else if (pe + 1 == 125) { VMCNT(0); }                               \
      if (pe + 1 <= 125) barrier_();                                      \
    }

    for (int kk = 0; kk < 32; ++kk) {
      UNIT15(2 * kk,     b0, b1)
      UNIT15(2 * kk + 1, b1, b0)
    }
#undef UNIT15
  } else {
    // 64 phases; B loaded every phase (consumed next).
    stageA(0); stageA(1); stageA(2);
    loadB(0, b0);
    VMCNT(6);
    barrier_();
    readA(0, a0);

#define PH15(U, AC, AN, BC, BN)                                           \
    {                                                                     \
      const int u_ = (U);                                                 \
      if (u_ <= 62) readA((u_ + 1) & 3, AN);                              \
      if (u_ <= 60) stageA(u_ + 3);                                       \
      if (u_ <= 62) loadB(u_ + 1, BN);                                    \
      SCHEDB();                                                           \
      mfma32(AC, BC);                                                     \
      if (u_ <= 60)      { VMCNT(6); }                                    \
      else if (u_ == 61) { VMCNT(0); }                                    \
      if (u_ <= 62) barrier_();                                           \
    }

    for (int j = 0; j < 32; ++j) {
      PH15(2 * j,     a0, a1, b0, b1)
      PH15(2 * j + 1, a1, a0, b1, b0)
    }
#undef PH15
  }

  // ---- epilogue: C/D layout col = lane&15, row = (lane>>4)*4 + reg
  const int row_base = by * 256 + wm + (lkr << 2);
  const int col_base = bx * 256 + wn + lm;
#pragma unroll
  for (int fm = 0; fm < 8; fm++)
#pragma unroll
    for (int fn = 0; fn < 4; fn++) {
      const int n = col_base + fn * 16;
      float bcol = 0.f;
      if constexpr (BIAS == 1) bcol = bias[n];
#pragma unroll
      for (int r = 0; r < 4; r++) {
        const int m = row_base + fm * 16 + r;
        float v = acc[fm][fn][r] * cscale;
        if constexpr (BIAS == 1) v += bcol;
        if constexpr (BIAS == 2) v += bias[m];
        const size_t ci = (size_t)bz * sC + (size_t)m * Sd + n;
        if constexpr (OUT == 0) ((float*)Cp)[ci] = v;
        else if constexpr (OUT == 1) ((_Float16*)Cp)[ci] = (_Float16)v;
        else if constexpr (OUT == 3) ((_Float16*)Cp)[ci] = (_Float16)(v * 16.0f);
        else {
          float sv = v * 16.0f;
          _Float16 hv = (_Float16)sv;
          ((_Float16*)Cp)[ci]  = hv;
          ((_Float16*)Clp)[ci] = (_Float16)(sv - (float)hv);
        }
      }
    }
}

// ---------------------------------------------------------------------------
// Row softmax: one 256-thread block per row of 2048 f32 -> fp16 probs.
// ---------------------------------------------------------------------------
__global__ __launch_bounds__(256) void softmax_rows(const float* __restrict__ X,
                                                    _Float16* __restrict__ P)
{
  __shared__ float red[4];
  const size_t row = blockIdx.x;
  const float* x = X + row * Sd;
  _Float16* p = P + row * Sd;
  const int t = threadIdx.x;
  float v[8];
  float mx = -1e30f;
#pragma unroll
  for (int i = 0; i < 8; i++) { v[i] = x[t + 256 * i]; mx = fmaxf(mx, v[i]); }
#pragma unroll
  for (int o = 32; o > 0; o >>= 1) mx = fmaxf(mx, __shfl_xor(mx, o, 64));
  if ((t & 63) == 0) red[t >> 6] = mx;
  __syncthreads();
  mx = fmaxf(fmaxf(red[0], red[1]), fmaxf(red[2], red[3]));
  __syncthreads();
  float s = 0.f;
#pragma unroll
  for (int i = 0; i < 8; i++) { v[i] = __expf(v[i] - mx); s += v[i]; }
#pragma unroll
  for (int o = 32; o > 0; o >>= 1) s += __shfl_xor(s, o, 64);
  if ((t & 63) == 0) red[t >> 6] = s;
  __syncthreads();
  s = red[0] + red[1] + red[2] + red[3];
  float inv = 1.f / s;
#pragma unroll
  for (int i = 0; i < 8; i++) p[t + 256 * i] = (_Float16)(v[i] * inv);
}

// ---------------------------------------------------------------------------
extern "C" void kernel_launch(void* const* d_in, const int* in_sizes, int n_in,
                              void* d_out, int out_size, void* d_ws, size_t ws_size,
                              hipStream_t stream)
{
  const float* query = (const float*)d_in[0];
  const float* key_  = (const float*)d_in[1];
  const float* value = (const float*)d_in[2];
  const float* Wq = (const float*)d_in[3];
  const float* bq = (const float*)d_in[4];
  const float* Wk = (const float*)d_in[5];
  const float* bk = (const float*)d_in[6];
  const float* Wv = (const float*)d_in[7];
  const float* bv = (const float*)d_in[8];

  char* ws = (char*)d_ws;
  char* ob = (char*)d_out;
  const size_t M64 = (size_t)NB * MAT * 2;   // 64 MiB

  _Float16* q_h  = (_Float16*)(ws);                 // A[0,64)
  _Float16* k_h  = (_Float16*)(ws);                 // A[0,64) (q dead)
  _Float16* k_l  = (_Float16*)(ws + M64);           // A[64,128)
  float*    qk   = (float*)(ws);                    // A as f32 (k dead)
  _Float16* qT_h = (_Float16*)(ws + 2 * M64);       // D[128,192)
  _Float16* qT_l = (_Float16*)(ws + 3 * M64);       // D[192,256)
  _Float16* P    = qT_h;                            // after qT dead
  _Float16* vT   = qT_l;
  _Float16* kk_h = (_Float16*)(ws + 4 * M64);       // E[256,320)
  _Float16* val_h = (_Float16*)(ws + 5 * M64);      // E[320,384)

  _Float16* wq_h = (_Float16*)(ob);
  _Float16* wq_l = (_Float16*)(ob + (MAT * 2));
  _Float16* wk_h = (_Float16*)(ob + 2 * (MAT * 2));
  _Float16* wv_h = (_Float16*)(ob + 3 * (MAT * 2));
  float* out = (float*)d_out;

  dim3 blk256(256), blk512(512);
  dim3 gg(512);   // 8 batches x 8x8 tiles of 256
  const long NQ8 = (long)NB * MAT / 8;
  const long NW8 = MAT / 8;

  // 1. presplit query (hi only, x16), Wq (hi+lo, x16)
  presplit<false><<<dim3(2048), blk256, 0, stream>>>(query, q_h, nullptr, NQ8, 16.f);
  presplit<true><<<dim3(2048), blk256, 0, stream>>>(Wq, wq_h, wq_l, NW8, 16.f);
  // 2. qT[e][s] = sum_d Wq[e][d]*query[s][d] + bq[e] (row bias), split out
  gemm15<2, 2, 2><<<gg, blk512, 0, stream>>>(wq_h, wq_l, 0, q_h, MAT,
                                             bq, 1.f / 256.f, qT_h, qT_l, MAT);
  // 3. presplit key_ (hi+lo, x16), Wk (hi only, x16)
  presplit<true><<<dim3(2048), blk256, 0, stream>>>(key_, k_h, k_l, NQ8, 16.f);
  presplit<false><<<dim3(2048), blk256, 0, stream>>>(Wk, wk_h, nullptr, NW8, 16.f);
  // 4. kk[s'][e] = sum_d key_[s'][d]*Wk[e][d] + bk[e] (col bias), hi-only out
  gemm15<2, 1, 3><<<gg, blk512, 0, stream>>>(k_h, k_l, MAT, wk_h, 0,
                                             bk, 1.f / 256.f, kk_h, nullptr, MAT);
  // 5. qk[e][s'] = sum_m qT[e][m]*kk[s'][m]  (f32 out)
  gemm15<2, 0, 0><<<gg, blk512, 0, stream>>>(qT_h, qT_l, MAT, kk_h, MAT,
                                             nullptr, 1.f / 256.f, qk, nullptr, MAT);
  // 6. P = row-softmax(qk), fp16
  softmax_rows<<<dim3(NB * Sd), blk256, 0, stream>>>(qk, P);
  // 7. presplit value (x1), Wv (x1)
  presplit<false><<<dim3(2048), blk256, 0, stream>>>(value, val_h, nullptr, NQ8, 1.f);
  presplit<false><<<dim3(2048), blk256, 0, stream>>>(Wv, wv_h, nullptr, NW8, 1.f);
  // 8. vT[d'][s'] = sum_d Wv[d'][d]*value[s'][d] + bv[d'] (row bias), fp16
  gemm15<1, 2, 1><<<gg, blk512, 0, stream>>>(wv_h, nullptr, 0, val_h, MAT,
                                             bv, 1.f, vT, nullptr, MAT);
  // 9. out[d'][e] = sum_s' vT[d'][s']*P[e][s']  (f32 -> d_out)
  gemm15<1, 0, 0><<<gg, blk512, 0, stream>>>(vT, nullptr, MAT, P, MAT,
                                             nullptr, 1.f, out, nullptr, MAT);
}

// Round 16
// 1164.717 us; speedup vs baseline: 1.1888x; 1.1888x over previous
//
#include <hip/hip_runtime.h>
#include <hip/hip_fp16.h>

// Workspace: 384 MiB.
//   A [0,128M):   q_h (64M) -> k_h/k_l -> qk (f32, 128M)
//   D [128,256M): qT_h/qT_l -> P (64M) + vT (64M)
//   E [256,384M): kk_h (64M) + val_h (64M)
// d_out scratch (dead before final GEMM): wq_h/l, wk_h, wv_h

using half8_t = __attribute__((ext_vector_type(8))) _Float16;
using f32x4   = __attribute__((ext_vector_type(4))) float;

static constexpr int NB = 8;
static constexpr int Sd = 2048;
static constexpr long MAT = (long)Sd * Sd;

__device__ __forceinline__ void gload16(const _Float16* g, _Float16* l) {
  __builtin_amdgcn_global_load_lds(
      (const __attribute__((address_space(1))) void*)g,
      (__attribute__((address_space(3))) void*)l, 16, 0, 0);
}
// r10-measured artifact reproduced exactly: memory-clobbered barrier
// and vmcnt — best measured configuration of this session; do not "improve".
__device__ __forceinline__ void barrier_() { asm volatile("s_barrier" ::: "memory"); }
#define VMCNT(n) asm volatile("s_waitcnt vmcnt(" #n ")" ::: "memory")
#define SCHEDB() __builtin_amdgcn_sched_barrier(0)

// ---------------------------------------------------------------------------
// presplit: f32 -> fp16 hi (+ residual lo if SPLIT), scaled.
// ---------------------------------------------------------------------------
template<bool SPLIT>
__global__ __launch_bounds__(256) void presplit(const float* __restrict__ in,
    _Float16* __restrict__ h, _Float16* __restrict__ l, long n8, float scl)
{
  long i = (long)blockIdx.x * 256 + threadIdx.x;
  const long stride = (long)gridDim.x * 256;
  for (; i < n8; i += stride) {
    const f32x4* p = (const f32x4*)(in + i * 8);
    f32x4 a = p[0], b = p[1];
    half8_t hh, ll;
#pragma unroll
    for (int j = 0; j < 4; j++) {
      float x = a[j] * scl; _Float16 hv = (_Float16)x;
      hh[j] = hv; if constexpr (SPLIT) ll[j] = (_Float16)(x - (float)hv);
      float y = b[j] * scl; _Float16 hw = (_Float16)y;
      hh[4 + j] = hw; if constexpr (SPLIT) ll[4 + j] = (_Float16)(y - (float)hw);
    }
    *(half8_t*)(h + i * 8) = hh;
    if constexpr (SPLIT) *(half8_t*)(l + i * 8) = ll;
  }
}

// ---------------------------------------------------------------------------
// gemm10 (B^T form): C[i][j] = cscale * sum_k A[i][k]*B[j][k] (+ bias)
// EXACT round-5/round-10 structure (best measured: 258 us split-GEMM):
// 256x256 tile, phase = K-half unit (256x32, 16KB), ring-of-4 per operand.
// Register frag double-buffer: phase p issues 12 ds_read_b128 for half p+1
// into the alternate frag set + stages half p+3 (4 global_load_lds), then
// 32 MFMA on the current set, then vmcnt(4) + ONE barrier per phase.
// 512 threads (8 waves, 2x4).
// NSEG: 1 plain (K=2048); 2 = K-concat split [Ah|Al]x[Bh|Bh] (K=4096).
// BIAS: 0 none, 1 bias[n], 2 bias[m].
// OUT: 0 f32, 1 fp16, 2 split fp16 (x16), 3 fp16 hi-only (x16).
// ---------------------------------------------------------------------------
template<int NSEG, int BIAS, int OUT>
__global__ __launch_bounds__(512, 2) void gemm10(
    const _Float16* __restrict__ Ah, const _Float16* __restrict__ Al, long sA,
    const _Float16* __restrict__ Bh, long sB,
    const float* __restrict__ bias, float cscale,
    void* __restrict__ Cp, void* __restrict__ Clp, long sC)
{
  constexpr int NT = NSEG * 32;     // K-tiles of 64
  __shared__ __align__(16) _Float16 LA[4][8192];   // ring of 4 half-units
  __shared__ __align__(16) _Float16 LB[4][8192];

  const int t = threadIdx.x, w = t >> 6, l = t & 63;

  // XCD swizzle: 512 wgs -> 64 consecutive per XCD (one batch per XCD)
  const int wg = blockIdx.x;
  const int swz = (wg & 7) * 64 + (wg >> 3);
  const int bz = swz >> 6, rem = swz & 63;
  const int by = rem >> 3, bx = rem & 7;

  const _Float16* PAh = Ah + (size_t)bz * sA + (size_t)(by * 256) * Sd;
  const _Float16* PBh = Bh + (size_t)bz * sB + (size_t)(bx * 256) * Sd;
  const _Float16* PAl = (NSEG == 2)
      ? Al + (size_t)bz * sA + (size_t)(by * 256) * Sd : PAh;

  // staging geometry: slot S = i*512 + t -> row 2*(S>>3)+(S&1),
  // k-slot lk = ((S&7)>>1) ^ ((S>>3)&3); dest LDS = linear slot*8.
  const int s7 = t & 7;
  const int lkS = (s7 >> 1) ^ ((t >> 3) & 3);
  const size_t srcoff = (size_t)(2 * (t >> 3) + (s7 & 1)) * Sd + lkS * 8;
  const int du0 = w * 512;

  // read geometry (inverse involution; measured conflict-free)
  const int wm = (w >> 2) * 128, wn = (w & 3) * 64;
  const int lm = l & 15, lkr = l >> 4;
  const int sprime = ((lkr ^ ((lm >> 1) & 3)) << 1) | (lm & 1);
  const int aoff = (wm >> 1) * 128 + (lm >> 1) * 128 + sprime * 16;
  const int boff = (wn >> 1) * 128 + (lm >> 1) * 128 + sprime * 16;

  // half hp -> source pointers / k offset
  auto srcA = [&](int hp) -> const _Float16* {
    if constexpr (NSEG == 2) return (hp >> 6) ? PAl : PAh;
    return PAh;
  };
  auto koOf = [&](int hp) -> int {
    if constexpr (NSEG == 2) return (hp & 63) * 32;
    return hp * 32;
  };
  auto stageH = [&](int hp) {   // 4 global_load_lds
    const int u = hp & 3;
    const _Float16* a = srcA(hp) + koOf(hp);
    const _Float16* b = PBh + koOf(hp);
    gload16(a + srcoff, LA[u] + du0);
    gload16(a + srcoff + (size_t)128 * Sd, LA[u] + du0 + 4096);
    gload16(b + srcoff, LB[u] + du0);
    gload16(b + srcoff + (size_t)128 * Sd, LB[u] + du0 + 4096);
  };

  f32x4 acc[8][4] = {};
  half8_t fA0[8], fB0[4], fA1[8], fB1[4];

  auto readF = [&](int u, half8_t (&fa)[8], half8_t (&fb)[4]) {  // 12 b128
#pragma unroll
    for (int f = 0; f < 8; f++)
      fa[f] = *(const half8_t*)((const char*)LA[u] + aoff + f * 1024);
#pragma unroll
    for (int n = 0; n < 4; n++)
      fb[n] = *(const half8_t*)((const char*)LB[u] + boff + n * 1024);
  };
  auto mfma32 = [&](const half8_t (&fa)[8], const half8_t (&fb)[4]) {
    __builtin_amdgcn_s_setprio(1);
#pragma unroll
    for (int f = 0; f < 8; f++)
#pragma unroll
      for (int n = 0; n < 4; n++)
        acc[f][n] = __builtin_amdgcn_mfma_f32_16x16x32_f16(fa[f], fb[n], acc[f][n], 0, 0, 0);
    __builtin_amdgcn_s_setprio(0);
  };

  // ---- prologue: stage halves 0,1,2; force 0,1; read half-0 frags
  stageH(0); stageH(1); stageH(2);
  VMCNT(4);            // 12 outstanding -> forces stage(0), stage(1)
  barrier_();
  readF(0, fA0, fB0);

  // ---- main loop: tiles j=0..NT-2 (two phases each), tile NT-1 peeled
  for (int j = 0; j < NT - 1; ++j) {
    const int p0 = 2 * j;
    // even phase p0: consume half p0, read half p0+1, stage half p0+3
    readF((p0 + 1) & 3, fA1, fB1);
    stageH(p0 + 3);
    SCHEDB();
    mfma32(fA0, fB0);
    VMCNT(4);          // forces stage(p0+2)
    barrier_();
    // odd phase p0+1: consume half p0+1, read half p0+2, stage half p0+4
    readF((p0 + 2) & 3, fA0, fB0);
    if (j < NT - 2) stageH(p0 + 4);
    SCHEDB();
    mfma32(fA1, fB1);
    if (j == NT - 2) { VMCNT(0); } else { VMCNT(4); }   // forces stage(p0+3)
    barrier_();
  }
  // ---- peeled last tile (j = NT-1): halves 2NT-2, 2NT-1
  {
    const int p0 = 2 * (NT - 1);
    readF((p0 + 1) & 3, fA1, fB1);
    SCHEDB();
    mfma32(fA0, fB0);
    SCHEDB();
    mfma32(fA1, fB1);
  }

  // ---- epilogue: C/D layout col = lane&15, row = (lane>>4)*4 + reg
  const int row_base = by * 256 + wm + (lkr << 2);
  const int col_base = bx * 256 + wn + lm;
#pragma unroll
  for (int fm = 0; fm < 8; fm++)
#pragma unroll
    for (int fn = 0; fn < 4; fn++) {
      const int n = col_base + fn * 16;
      float bcol = 0.f;
      if constexpr (BIAS == 1) bcol = bias[n];
#pragma unroll
      for (int r = 0; r < 4; r++) {
        const int m = row_base + fm * 16 + r;
        float v = acc[fm][fn][r] * cscale;
        if constexpr (BIAS == 1) v += bcol;
        if constexpr (BIAS == 2) v += bias[m];
        const size_t ci = (size_t)bz * sC + (size_t)m * Sd + n;
        if constexpr (OUT == 0) ((float*)Cp)[ci] = v;
        else if constexpr (OUT == 1) ((_Float16*)Cp)[ci] = (_Float16)v;
        else if constexpr (OUT == 3) ((_Float16*)Cp)[ci] = (_Float16)(v * 16.0f);
        else {
          float sv = v * 16.0f;
          _Float16 hv = (_Float16)sv;
          ((_Float16*)Cp)[ci]  = hv;
          ((_Float16*)Clp)[ci] = (_Float16)(sv - (float)hv);
        }
      }
    }
}

// ---------------------------------------------------------------------------
// Row softmax: one 256-thread block per row of 2048 f32 -> fp16 probs.
// ---------------------------------------------------------------------------
__global__ __launch_bounds__(256) void softmax_rows(const float* __restrict__ X,
                                                    _Float16* __restrict__ P)
{
  __shared__ float red[4];
  const size_t row = blockIdx.x;
  const float* x = X + row * Sd;
  _Float16* p = P + row * Sd;
  const int t = threadIdx.x;
  float v[8];
  float mx = -1e30f;
#pragma unroll
  for (int i = 0; i < 8; i++) { v[i] = x[t + 256 * i]; mx = fmaxf(mx, v[i]); }
#pragma unroll
  for (int o = 32; o > 0; o >>= 1) mx = fmaxf(mx, __shfl_xor(mx, o, 64));
  if ((t & 63) == 0) red[t >> 6] = mx;
  __syncthreads();
  mx = fmaxf(fmaxf(red[0], red[1]), fmaxf(red[2], red[3]));
  __syncthreads();
  float s = 0.f;
#pragma unroll
  for (int i = 0; i < 8; i++) { v[i] = __expf(v[i] - mx); s += v[i]; }
#pragma unroll
  for (int o = 32; o > 0; o >>= 1) s += __shfl_xor(s, o, 64);
  if ((t & 63) == 0) red[t >> 6] = s;
  __syncthreads();
  s = red[0] + red[1] + red[2] + red[3];
  float inv = 1.f / s;
#pragma unroll
  for (int i = 0; i < 8; i++) p[t + 256 * i] = (_Float16)(v[i] * inv);
}

// ---------------------------------------------------------------------------
extern "C" void kernel_launch(void* const* d_in, const int* in_sizes, int n_in,
                              void* d_out, int out_size, void* d_ws, size_t ws_size,
                              hipStream_t stream)
{
  const float* query = (const float*)d_in[0];
  const float* key_  = (const float*)d_in[1];
  const float* value = (const float*)d_in[2];
  const float* Wq = (const float*)d_in[3];
  const float* bq = (const float*)d_in[4];
  const float* Wk = (const float*)d_in[5];
  const float* bk = (const float*)d_in[6];
  const float* Wv = (const float*)d_in[7];
  const float* bv = (const float*)d_in[8];

  char* ws = (char*)d_ws;
  char* ob = (char*)d_out;
  const size_t M64 = (size_t)NB * MAT * 2;   // 64 MiB

  _Float16* q_h  = (_Float16*)(ws);                 // A[0,64)
  _Float16* k_h  = (_Float16*)(ws);                 // A[0,64) (q dead)
  _Float16* k_l  = (_Float16*)(ws + M64);           // A[64,128)
  float*    qk   = (float*)(ws);                    // A as f32 (k dead)
  _Float16* qT_h = (_Float16*)(ws + 2 * M64);       // D[128,192)
  _Float16* qT_l = (_Float16*)(ws + 3 * M64);       // D[192,256)
  _Float16* P    = qT_h;                            // after qT dead
  _Float16* vT   = qT_l;
  _Float16* kk_h = (_Float16*)(ws + 4 * M64);       // E[256,320)
  _Float16* val_h = (_Float16*)(ws + 5 * M64);      // E[320,384)

  _Float16* wq_h = (_Float16*)(ob);
  _Float16* wq_l = (_Float16*)(ob + (MAT * 2));
  _Float16* wk_h = (_Float16*)(ob + 2 * (MAT * 2));
  _Float16* wv_h = (_Float16*)(ob + 3 * (MAT * 2));
  float* out = (float*)d_out;

  dim3 blk256(256), blk512(512);
  dim3 gg(512);   // 8 batches x 8x8 tiles of 256
  const long NQ8 = (long)NB * MAT / 8;
  const long NW8 = MAT / 8;

  // 1. presplit query (hi only, x16), Wq (hi+lo, x16)
  presplit<false><<<dim3(2048), blk256, 0, stream>>>(query, q_h, nullptr, NQ8, 16.f);
  presplit<true><<<dim3(2048), blk256, 0, stream>>>(Wq, wq_h, wq_l, NW8, 16.f);
  // 2. qT[e][s] = sum_d Wq[e][d]*query[s][d] + bq[e] (row bias), split out
  gemm10<2, 2, 2><<<gg, blk512, 0, stream>>>(wq_h, wq_l, 0, q_h, MAT,
                                             bq, 1.f / 256.f, qT_h, qT_l, MAT);
  // 3. presplit key_ (hi+lo, x16), Wk (hi only, x16)
  presplit<true><<<dim3(2048), blk256, 0, stream>>>(key_, k_h, k_l, NQ8, 16.f);
  presplit<false><<<dim3(2048), blk256, 0, stream>>>(Wk, wk_h, nullptr, NW8, 16.f);
  // 4. kk[s'][e] = sum_d key_[s'][d]*Wk[e][d] + bk[e] (col bias), hi-only out
  gemm10<2, 1, 3><<<gg, blk512, 0, stream>>>(k_h, k_l, MAT, wk_h, 0,
                                             bk, 1.f / 256.f, kk_h, nullptr, MAT);
  // 5. qk[e][s'] = sum_m qT[e][m]*kk[s'][m]  (f32 out)
  gemm10<2, 0, 0><<<gg, blk512, 0, stream>>>(qT_h, qT_l, MAT, kk_h, MAT,
                                             nullptr, 1.f / 256.f, qk, nullptr, MAT);
  // 6. P = row-softmax(qk), fp16
  softmax_rows<<<dim3(NB * Sd), blk256, 0, stream>>>(qk, P);
  // 7. presplit value (x1), Wv (x1)
  presplit<false><<<dim3(2048), blk256, 0, stream>>>(value, val_h, nullptr, NQ8, 1.f);
  presplit<false><<<dim3(2048), blk256, 0, stream>>>(Wv, wv_h, nullptr, NW8, 1.f);
  // 8. vT[d'][s'] = sum_d Wv[d'][d]*value[s'][d] + bv[d'] (row bias), fp16
  gemm10<1, 2, 1><<<gg, blk512, 0, stream>>>(wv_h, nullptr, 0, val_h, MAT,
                                             bv, 1.f, vT, nullptr, MAT);
  // 9. out[d'][e] = sum_s' vT[d'][s']*P[e][s']  (f32 -> d_out)
  gemm10<1, 0, 0><<<gg, blk512, 0, stream>>>(vT, nullptr, MAT, P, MAT,
                                             nullptr, 1.f, out, nullptr, MAT);
}